// Round 2
// baseline (384.093 us; speedup 1.0000x reference)
//
#include <hip/hip_runtime.h>
#include <hip/hip_bf16.h>
#include <stdint.h>

#define N_NODES_C 1000000
#define N_GRAPHS_C 4096
#define SPAN 96   // block-local denom table: 128 consecutive nodes span <=3 graphs (96 = margin)

typedef __attribute__((ext_vector_type(8))) __bf16 bf16x8;
typedef __attribute__((ext_vector_type(2))) __bf16 bf16x2;
typedef __attribute__((ext_vector_type(4))) float f32x4;

__device__ __forceinline__ unsigned short f2bf(float f) {
    union { float f; unsigned int u; } v; v.f = f;
    unsigned int r = v.u + 0x7FFFu + ((v.u >> 16) & 1u);   // RNE
    return (unsigned short)(r >> 16);
}
__device__ __forceinline__ unsigned int pack2(float a, float b) {
#if __has_builtin(__builtin_amdgcn_cvt_pk_bf16_f32)
    bf16x2 r = __builtin_amdgcn_cvt_pk_bf16_f32(a, b);
    union { bf16x2 v; unsigned int u; } cv; cv.v = r;
    return cv.u;
#else
    return (unsigned int)f2bf(a) | ((unsigned int)f2bf(b) << 16);
#endif
}

// Stage 0: per-graph bias c[b][j] = bn[j] + (global_attr[b]@Wg + bg) @ Wn_bot[:,j]
// 4 graphs per 256-thread block; Wn_bot staged once per block in LDS.
// Block 0 additionally emits BT (Wn_top^T in bf16); every block zeroes its 4 denoms.
__global__ __launch_bounds__(256) void stage0_kernel(
    const float* __restrict__ ga, const float* __restrict__ Wg,
    const float* __restrict__ bg, const float* __restrict__ Wn,
    const float* __restrict__ bn,
    float* __restrict__ c, unsigned short* __restrict__ BT,
    float* __restrict__ denom)
{
    __shared__ float Wns[64 * 64];   // Wn rows 64..127 (16 KB)
    __shared__ float gs[4][64];
    int t = threadIdx.x;
#pragma unroll
    for (int i = 0; i < 4; ++i)
        ((float4*)Wns)[t + i * 256] = ((const float4*)(Wn + 64 * 64))[t + i * 256];
    if (blockIdx.x == 0) {
#pragma unroll
        for (int i = 0; i < 16; ++i) {
            int flat = t * 16 + i;           // BT[n][k] = Wn[k][n]
            int n = flat >> 6, k = flat & 63;
            BT[flat] = f2bf(Wn[k * 64 + n]);
        }
    }
    int gl = t >> 6, j = t & 63;
    int b = blockIdx.x * 4 + gl;
    float acc = bg[j];
#pragma unroll
    for (int m = 0; m < 3; ++m) acc += ga[b * 3 + m] * Wg[m * 64 + j];
    gs[gl][j] = acc;
    __syncthreads();
    float cj = bn[j];
#pragma unroll 16
    for (int k = 0; k < 64; ++k) cj += gs[gl][k] * Wns[k * 64 + j];
    c[b * 64 + j] = cj;
    if (j == 0) denom[b] = 0.0f;
}

// Main: TWO 16-node tiles per wave (32 nodes/wave), 4 waves/block = 128 nodes/block.
// 8 dwordx4 loads in flight per lane (2x the MLP of the 1-tile version); B fragments,
// wa, and the barrier/atomic tail amortized over 2 tiles. Denom contributions
// aggregated per-block in LDS (sorted segments), ~1-3 global atomics/block.
__global__ __launch_bounds__(256, 4) void node_kernel(
    const float* __restrict__ x, const int* __restrict__ nb,
    const float* __restrict__ c, const unsigned short* __restrict__ BT,
    const float* __restrict__ Wa, const float* __restrict__ ba,
    float* __restrict__ e, float* __restrict__ denom)
{
    __shared__ float part[SPAN];
    int t = threadIdx.x;
    int wave = t >> 6, lane = t & 63;
    int quad = lane >> 4, l15 = lane & 15;
    int blockbase = blockIdx.x * 128;
    int base0 = blockbase + wave * 16;            // tile 0: first 64 nodes of block
    int base1 = blockbase + 64 + wave * 16;       // tile 1: second 64 nodes
    bool has2 = (blockbase + 128) <= N_NODES_C;   // last block (7812) has only tile 0
    bool is64 = nb[N_NODES_C - 1] < 1024;         // int64 low/high-word layout vs int32

    if (t < SPAN) part[t] = 0.0f;

    // x loads for both tiles issued back-to-back: 8 dwordx4 in flight per lane
    const float4* xp0 = (const float4*)(x + (long)(base0 + l15) * 64);
    float4 v0 = xp0[quad * 2];
    float4 v1 = xp0[quad * 2 + 1];
    float4 v2 = xp0[8 + quad * 2];
    float4 v3 = xp0[8 + quad * 2 + 1];
    float4 w0, w1, w2, w3;
    if (has2) {
        const float4* xp1 = (const float4*)(x + (long)(base1 + l15) * 64);
        w0 = xp1[quad * 2];
        w1 = xp1[quad * 2 + 1];
        w2 = xp1[8 + quad * 2];
        w3 = xp1[8 + quad * 2 + 1];
    }

    // Segment ids: coalesced loads, distributed by shuffle
    int g0 = is64 ? nb[2L * blockbase] : nb[blockbase];
    int segown0 = is64 ? nb[2L * (base0 + l15)] : nb[base0 + l15];
    int sg00 = __shfl(segown0, quad * 4 + 0, 64);
    int sg01 = __shfl(segown0, quad * 4 + 1, 64);
    int sg02 = __shfl(segown0, quad * 4 + 2, 64);
    int sg03 = __shfl(segown0, quad * 4 + 3, 64);
    int sg10 = 0, sg11 = 0, sg12 = 0, sg13 = 0;
    if (has2) {
        int segown1 = is64 ? nb[2L * (base1 + l15)] : nb[base1 + l15];
        sg10 = __shfl(segown1, quad * 4 + 0, 64);
        sg11 = __shfl(segown1, quad * 4 + 1, 64);
        sg12 = __shfl(segown1, quad * 4 + 2, 64);
        sg13 = __shfl(segown1, quad * 4 + 3, 64);
    }

    // B fragments: B[k][n], lane holds n = l15 (+16*nt), k = quad*8 + j (+32*kh)
    bf16x8 b0[4], b1[4];
#pragma unroll
    for (int nt = 0; nt < 4; ++nt) {
        b0[nt] = *(const bf16x8*)&BT[(nt * 16 + l15) * 64 + quad * 8];
        b1[nt] = *(const bf16x8*)&BT[(nt * 16 + l15) * 64 + quad * 8 + 32];
    }
    float wa[4];
    float bav = ba[0];
#pragma unroll
    for (int nt = 0; nt < 4; ++nt) wa[nt] = Wa[nt * 16 + l15];

    // Tile 0 MFMA
    union { bf16x8 v; unsigned int u[4]; } P0, P1;
    P0.u[0] = pack2(v0.x, v0.y); P0.u[1] = pack2(v0.z, v0.w);
    P0.u[2] = pack2(v1.x, v1.y); P0.u[3] = pack2(v1.z, v1.w);
    P1.u[0] = pack2(v2.x, v2.y); P1.u[1] = pack2(v2.z, v2.w);
    P1.u[2] = pack2(v3.x, v3.y); P1.u[3] = pack2(v3.z, v3.w);
    f32x4 acc0[4];
#pragma unroll
    for (int nt = 0; nt < 4; ++nt) {
        acc0[nt] = (f32x4){0.f, 0.f, 0.f, 0.f};
        acc0[nt] = __builtin_amdgcn_mfma_f32_16x16x32_bf16(P0.v, b0[nt], acc0[nt], 0, 0, 0);
        acc0[nt] = __builtin_amdgcn_mfma_f32_16x16x32_bf16(P1.v, b1[nt], acc0[nt], 0, 0, 0);
    }

    // Tile 1 MFMA
    f32x4 acc1[4];
    if (has2) {
        union { bf16x8 v; unsigned int u[4]; } Q0, Q1;
        Q0.u[0] = pack2(w0.x, w0.y); Q0.u[1] = pack2(w0.z, w0.w);
        Q0.u[2] = pack2(w1.x, w1.y); Q0.u[3] = pack2(w1.z, w1.w);
        Q1.u[0] = pack2(w2.x, w2.y); Q1.u[1] = pack2(w2.z, w2.w);
        Q1.u[2] = pack2(w3.x, w3.y); Q1.u[3] = pack2(w3.z, w3.w);
#pragma unroll
        for (int nt = 0; nt < 4; ++nt) {
            acc1[nt] = (f32x4){0.f, 0.f, 0.f, 0.f};
            acc1[nt] = __builtin_amdgcn_mfma_f32_16x16x32_bf16(Q0.v, b0[nt], acc1[nt], 0, 0, 0);
            acc1[nt] = __builtin_amdgcn_mfma_f32_16x16x32_bf16(Q1.v, b1[nt], acc1[nt], 0, 0, 0);
        }
    }

    __syncthreads();   // part[] zeroed before any leader writes

    // ---- Epilogue tile 0. C/D layout: col = l15 + 16*nt, rows = base + quad*4 + reg
    {
        int r0 = base0 + quad * 4;
        bool uni = (sg00 == sg03);
        float sp0 = 0.f, sp1 = 0.f, sp2 = 0.f, sp3 = 0.f;
#pragma unroll
        for (int nt = 0; nt < 4; ++nt) {
            int col = nt * 16 + l15;
            float c0, c1, c2, c3;
            if (uni) { c0 = c[sg00 * 64 + col]; c1 = c0; c2 = c0; c3 = c0; }
            else {
                c0 = c[sg00 * 64 + col]; c1 = c[sg01 * 64 + col];
                c2 = c[sg02 * 64 + col]; c3 = c[sg03 * 64 + col];
            }
            float y0 = acc0[nt].x + c0, y1 = acc0[nt].y + c1;
            float y2 = acc0[nt].z + c2, y3 = acc0[nt].w + c3;
            sp0 += __logf(1.f + __expf(y0)) * wa[nt];
            sp1 += __logf(1.f + __expf(y1)) * wa[nt];
            sp2 += __logf(1.f + __expf(y2)) * wa[nt];
            sp3 += __logf(1.f + __expf(y3)) * wa[nt];
        }
#pragma unroll
        for (int off = 1; off < 16; off <<= 1) {   // xor 1,2,4,8 stays inside the quad
            sp0 += __shfl_xor(sp0, off, 64);
            sp1 += __shfl_xor(sp1, off, 64);
            sp2 += __shfl_xor(sp2, off, 64);
            sp3 += __shfl_xor(sp3, off, 64);
        }
        float e0 = __expf(sp0 + bav), e1 = __expf(sp1 + bav);
        float e2 = __expf(sp2 + bav), e3 = __expf(sp3 + bav);
        if (l15 == 0) {
            *(float4*)&e[r0] = make_float4(e0, e1, e2, e3);
            float s = e0; int cur = sg00;
            if (sg01 == cur) s += e1; else {
                unsigned int i0 = cur - g0;
                if (i0 < SPAN) atomicAdd(&part[i0], s); else atomicAdd(&denom[cur], s);
                cur = sg01; s = e1;
            }
            if (sg02 == cur) s += e2; else {
                unsigned int i0 = cur - g0;
                if (i0 < SPAN) atomicAdd(&part[i0], s); else atomicAdd(&denom[cur], s);
                cur = sg02; s = e2;
            }
            if (sg03 == cur) s += e3; else {
                unsigned int i0 = cur - g0;
                if (i0 < SPAN) atomicAdd(&part[i0], s); else atomicAdd(&denom[cur], s);
                cur = sg03; s = e3;
            }
            unsigned int i0 = cur - g0;
            if (i0 < SPAN) atomicAdd(&part[i0], s); else atomicAdd(&denom[cur], s);
        }
    }

    // ---- Epilogue tile 1
    if (has2) {
        int r0 = base1 + quad * 4;
        bool uni = (sg10 == sg13);
        float sp0 = 0.f, sp1 = 0.f, sp2 = 0.f, sp3 = 0.f;
#pragma unroll
        for (int nt = 0; nt < 4; ++nt) {
            int col = nt * 16 + l15;
            float c0, c1, c2, c3;
            if (uni) { c0 = c[sg10 * 64 + col]; c1 = c0; c2 = c0; c3 = c0; }
            else {
                c0 = c[sg10 * 64 + col]; c1 = c[sg11 * 64 + col];
                c2 = c[sg12 * 64 + col]; c3 = c[sg13 * 64 + col];
            }
            float y0 = acc1[nt].x + c0, y1 = acc1[nt].y + c1;
            float y2 = acc1[nt].z + c2, y3 = acc1[nt].w + c3;
            sp0 += __logf(1.f + __expf(y0)) * wa[nt];
            sp1 += __logf(1.f + __expf(y1)) * wa[nt];
            sp2 += __logf(1.f + __expf(y2)) * wa[nt];
            sp3 += __logf(1.f + __expf(y3)) * wa[nt];
        }
#pragma unroll
        for (int off = 1; off < 16; off <<= 1) {
            sp0 += __shfl_xor(sp0, off, 64);
            sp1 += __shfl_xor(sp1, off, 64);
            sp2 += __shfl_xor(sp2, off, 64);
            sp3 += __shfl_xor(sp3, off, 64);
        }
        float e0 = __expf(sp0 + bav), e1 = __expf(sp1 + bav);
        float e2 = __expf(sp2 + bav), e3 = __expf(sp3 + bav);
        if (l15 == 0) {
            *(float4*)&e[r0] = make_float4(e0, e1, e2, e3);
            float s = e0; int cur = sg10;
            if (sg11 == cur) s += e1; else {
                unsigned int i0 = cur - g0;
                if (i0 < SPAN) atomicAdd(&part[i0], s); else atomicAdd(&denom[cur], s);
                cur = sg11; s = e1;
            }
            if (sg12 == cur) s += e2; else {
                unsigned int i0 = cur - g0;
                if (i0 < SPAN) atomicAdd(&part[i0], s); else atomicAdd(&denom[cur], s);
                cur = sg12; s = e2;
            }
            if (sg13 == cur) s += e3; else {
                unsigned int i0 = cur - g0;
                if (i0 < SPAN) atomicAdd(&part[i0], s); else atomicAdd(&denom[cur], s);
                cur = sg13; s = e3;
            }
            unsigned int i0 = cur - g0;
            if (i0 < SPAN) atomicAdd(&part[i0], s); else atomicAdd(&denom[cur], s);
        }
    }

    __syncthreads();
    if (t < SPAN) {
        float v = part[t];
        if (v != 0.0f) atomicAdd(&denom[g0 + t], v);
    }
}

// Finalize: w = e / denom[seg]
__global__ __launch_bounds__(256) void fin_kernel(
    const float* __restrict__ e, const int* __restrict__ nb,
    const float* __restrict__ denom, float* __restrict__ out)
{
    long node0 = (long)(blockIdx.x * 256 + threadIdx.x) * 4;
    if (node0 >= N_NODES_C) return;
    bool is64 = nb[N_NODES_C - 1] < 1024;
    float4 ev = *(const float4*)&e[node0];
    int s0, s1, s2, s3;
    if (is64) {
        int4 a = *(const int4*)&nb[2 * node0];
        int4 b = *(const int4*)&nb[2 * node0 + 4];
        s0 = a.x; s1 = a.z; s2 = b.x; s3 = b.z;
    } else {
        int4 a = *(const int4*)&nb[node0];
        s0 = a.x; s1 = a.y; s2 = a.z; s3 = a.w;
    }
    float4 w;
    w.x = ev.x / denom[s0];
    w.y = ev.y / denom[s1];
    w.z = ev.z / denom[s2];
    w.w = ev.w / denom[s3];
    *(float4*)&out[node0] = w;
}

extern "C" void kernel_launch(void* const* d_in, const int* in_sizes, int n_in,
                              void* d_out, int out_size, void* d_ws, size_t ws_size,
                              hipStream_t stream) {
    const float* x  = (const float*)d_in[0];
    const int*   nb = (const int*)d_in[1];
    const float* ga = (const float*)d_in[2];
    const float* Wg = (const float*)d_in[3];
    const float* bg = (const float*)d_in[4];
    const float* Wn = (const float*)d_in[5];
    const float* bn = (const float*)d_in[6];
    const float* Wa = (const float*)d_in[7];
    const float* ba = (const float*)d_in[8];

    char* ws = (char*)d_ws;
    float* e            = (float*)(ws);                              // 4,000,000 B
    float* c            = (float*)(ws + 4194304);                    // 1 MB
    unsigned short* BT  = (unsigned short*)(ws + 4194304 + 1048576); // 8 KB
    float* denom        = (float*)(ws + 4194304 + 1048576 + 8192);   // 16 KB

    hipLaunchKernelGGL(stage0_kernel, dim3(N_GRAPHS_C / 4), dim3(256), 0, stream,
                       ga, Wg, bg, Wn, bn, c, BT, denom);
    hipLaunchKernelGGL(node_kernel, dim3((N_NODES_C + 127) / 128), dim3(256), 0, stream,
                       x, nb, c, BT, Wa, ba, e, denom);
    hipLaunchKernelGGL(fin_kernel, dim3((N_NODES_C / 4 + 255) / 256), dim3(256), 0, stream,
                       e, nb, denom, (float*)d_out);
}